// Round 2
// baseline (167.113 us; speedup 1.0000x reference)
//
#include <hip/hip_runtime.h>

#define D        128
#define K2       256
#define M_TILE   32
#define THREADS  512
#define B_ROWS   131072
#define NTILES   (B_ROWS / M_TILE)   // 4096
#define GRID_BLOCKS 512

typedef __bf16  bf16x8  __attribute__((ext_vector_type(8)));
typedef float   f32x4   __attribute__((ext_vector_type(4)));

#define LOG2E 1.4426950408889634f

__device__ __forceinline__ float fexp2(float x) { return __builtin_amdgcn_exp2f(x); }
__device__ __forceinline__ float frcp(float x)  { return __builtin_amdgcn_rcpf(x); }

// tanh(x) = 1 - 2/(e^{2x}+1); inf-safe: e->inf => rcp->0 => 1; e->0 => -1
__device__ __forceinline__ float fast_tanh(float x) {
    float e = fexp2(x * (2.f * LOG2E));
    return 1.f - 2.f * frcp(e + 1.f);
}
// sigmoid(x) = 1/(1+e^{-x}); inf-safe
__device__ __forceinline__ float fast_sigmoid(float x) {
    return frcp(1.f + fexp2(-LOG2E * x));
}

__global__ __launch_bounds__(THREADS, 4)
void liquid_cell(const float* __restrict__ x,      const float* __restrict__ st,
                 const float* __restrict__ w_in,   const float* __restrict__ b_in,
                 const float* __restrict__ w_rec,  const float* __restrict__ w_gate,
                 const float* __restrict__ b_gate, const float* __restrict__ bias,
                 const float* __restrict__ log_step,
                 const float* __restrict__ gamma,  const float* __restrict__ beta,
                 float* __restrict__ out)
{
    // double-buffered A tiles, XOR-swizzled (elem ^= (row&7)<<3  <=> byte ^= (row&7)<<4)
    __shared__ __align__(16) __bf16 A1[2][M_TILE * 256];  // [x | tanh(state)]
    __shared__ __align__(16) __bf16 A2[2][M_TILE * 256];  // LN([x|state]) (gamma/beta folded into W)
    __shared__ float2 MUB[2][M_TILE];                     // {mu, std} per row for state reconstruction

    const int tid  = threadIdx.x;
    const int lane = tid & 63;
    const int wave = tid >> 6;
    const int q    = lane >> 4;            // 0..3
    const int arow = lane & 15;
    const int hcol = wave * 16 + arow;     // output col owned in epilogue / weight row
    const int koff = q * 8;

    // ---- per-thread output params (regs, no LDS) ----
    float stepv = fast_sigmoid(log_step[hcol]);
    float bd    = b_in[hcol] + bias[hcol];
    float bg    = b_gate[hcol];

    // ---- persistent weight B-fragments; fold gamma into w_gate, beta into bg ----
    bf16x8 wd[8], wg[8];
    float betaAcc = 0.f;
    #pragma unroll
    for (int kb = 0; kb < 8; ++kb) {
        const int k = kb * 32 + koff;
        const float* s1 = (k < 128) ? (w_in  + hcol * 128 + k)
                                    : (w_rec + hcol * 128 + (k - 128));
        const float* s2 = w_gate + hcol * 256 + k;
        #pragma unroll
        for (int j = 0; j < 8; ++j) {
            wd[kb][j] = (__bf16)s1[j];
            float wv  = s2[j];
            wg[kb][j] = (__bf16)(wv * gamma[k + j]);
            betaAcc  += wv * beta[k + j];
        }
    }
    betaAcc += __shfl_xor(betaAcc, 16);
    betaAcc += __shfl_xor(betaAcc, 32);
    bg += betaAcc;   // gate_in = LN0(gi)·(γ⊙Wg)^T + (b_gate + β·Wg^T)

    const int r   = tid >> 4;              // row within tile, 0..31
    const int c0  = (tid & 15) * 8;        // 8-col chunk
    const int sw  = (r & 7) << 3;          // write-side swizzle (elem units)
    const int rswA = (arow & 7) << 3;      // read-side swizzle (row&7 == arow&7 for both ms)

    // ---- prefetch tile 0 ----
    {
        const float* xp = x  + ((long)blockIdx.x * M_TILE + r) * D + c0;
        const float* sp = st + ((long)blockIdx.x * M_TILE + r) * D + c0;
    }
    f32x4 xa, xb, sa, sb;
    {
        const float* xp = x  + ((long)blockIdx.x * M_TILE + r) * D + c0;
        const float* sp = st + ((long)blockIdx.x * M_TILE + r) * D + c0;
        xa = *(const f32x4*)xp;       xb = *(const f32x4*)(xp + 4);
        sa = *(const f32x4*)sp;       sb = *(const f32x4*)(sp + 4);
    }

    int buf = 0;
    for (int tile = blockIdx.x; tile < NTILES; tile += GRID_BLOCKS) {
        // ---- phase A: LN stats + bf16 tiles (consumes xa..sb) ----
        float sum = 0.f, sq = 0.f;
        #pragma unroll
        for (int j = 0; j < 4; ++j) {
            sum += xa[j] + xb[j] + sa[j] + sb[j];
            sq  += xa[j]*xa[j] + xb[j]*xb[j] + sa[j]*sa[j] + sb[j]*sb[j];
        }
        #pragma unroll
        for (int m = 1; m < 16; m <<= 1) {
            sum += __shfl_xor(sum, m);
            sq  += __shfl_xor(sq,  m);
        }
        const float mu   = sum * (1.f / 256.f);
        const float var  = sq  * (1.f / 256.f) - mu * mu;
        const float rstd = __builtin_amdgcn_rsqf(var + 1e-5f);
        const float stdv = __builtin_amdgcn_sqrtf(var + 1e-5f);

        bf16x8 a1x, a1s, a2x, a2s;
        #pragma unroll
        for (int j = 0; j < 4; ++j) {
            a1x[j]     = (__bf16)xa[j];
            a1x[j + 4] = (__bf16)xb[j];
            a1s[j]     = (__bf16)fast_tanh(sa[j]);
            a1s[j + 4] = (__bf16)fast_tanh(sb[j]);
            a2x[j]     = (__bf16)((xa[j] - mu) * rstd);
            a2x[j + 4] = (__bf16)((xb[j] - mu) * rstd);
            a2s[j]     = (__bf16)((sa[j] - mu) * rstd);
            a2s[j + 4] = (__bf16)((sb[j] - mu) * rstd);
        }

        *(bf16x8*)&A1[buf][(r * 256 +       c0) ^ sw] = a1x;
        *(bf16x8*)&A1[buf][(r * 256 + 128 + c0) ^ sw] = a1s;
        *(bf16x8*)&A2[buf][(r * 256 +       c0) ^ sw] = a2x;
        *(bf16x8*)&A2[buf][(r * 256 + 128 + c0) ^ sw] = a2s;
        if ((tid & 15) == 0) MUB[buf][r] = make_float2(mu, stdv);

        // ---- prefetch next tile into the same regs (hides under MFMA+epilogue) ----
        const int next = tile + GRID_BLOCKS;
        if (next < NTILES) {
            const float* xpn = x  + ((long)next * M_TILE + r) * D + c0;
            const float* spn = st + ((long)next * M_TILE + r) * D + c0;
            xa = *(const f32x4*)xpn;  xb = *(const f32x4*)(xpn + 4);
            sa = *(const f32x4*)spn;  sb = *(const f32x4*)(spn + 4);
        }

        __syncthreads();   // single barrier per tile (double-buffered LDS)

        // ---- MFMA ----
        f32x4 acc1[2], acc2[2];
        #pragma unroll
        for (int ms = 0; ms < 2; ++ms) { acc1[ms] = (f32x4)(0.f); acc2[ms] = (f32x4)(0.f); }

        #pragma unroll
        for (int ms = 0; ms < 2; ++ms) {
            const int base = (ms * 16 + arow) * 256;
            #pragma unroll
            for (int kb = 0; kb < 8; ++kb) {
                bf16x8 a = *(const bf16x8*)&A1[buf][base + ((kb * 32 + koff) ^ rswA)];
                acc1[ms] = __builtin_amdgcn_mfma_f32_16x16x32_bf16(a, wd[kb], acc1[ms], 0, 0, 0);
            }
            #pragma unroll
            for (int kb = 0; kb < 8; ++kb) {
                bf16x8 a = *(const bf16x8*)&A2[buf][base + ((kb * 32 + koff) ^ rswA)];
                acc2[ms] = __builtin_amdgcn_mfma_f32_16x16x32_bf16(a, wg[kb], acc2[ms], 0, 0, 0);
            }
        }

        // ---- epilogue: reconstruct state from A2, activation + blend + store ----
        const long obase = (long)tile * M_TILE;
        #pragma unroll
        for (int ms = 0; ms < 2; ++ms) {
            #pragma unroll
            for (int rg = 0; rg < 4; ++rg) {
                const int row = ms * 16 + q * 4 + rg;
                const float2 m = MUB[buf][row];
                const float a2v = (float)A2[buf][(row * 256 + 128 + hcol) ^ ((row & 7) << 3)];
                const float s   = a2v * m.y + m.x;          // state reconstructed
                const float target = fast_tanh(acc1[ms][rg] + bd);
                const float gate   = fast_sigmoid(acc2[ms][rg] + bg);
                const float blend  = fminf(stepv * gate, 1.f);
                out[(obase + row) * D + hcol] = s + blend * (target - s);
            }
        }
        buf ^= 1;
    }
}

extern "C" void kernel_launch(void* const* d_in, const int* in_sizes, int n_in,
                              void* d_out, int out_size, void* d_ws, size_t ws_size,
                              hipStream_t stream) {
    const float* x        = (const float*)d_in[0];
    const float* st       = (const float*)d_in[1];
    const float* w_in     = (const float*)d_in[2];
    const float* b_in     = (const float*)d_in[3];
    const float* w_rec    = (const float*)d_in[4];
    const float* w_gate   = (const float*)d_in[5];
    const float* b_gate   = (const float*)d_in[6];
    const float* bias     = (const float*)d_in[7];
    const float* log_step = (const float*)d_in[8];
    const float* gamma    = (const float*)d_in[9];
    const float* beta     = (const float*)d_in[10];
    float* out = (float*)d_out;

    hipLaunchKernelGGL(liquid_cell, dim3(GRID_BLOCKS), dim3(THREADS), 0, stream,
                       x, st, w_in, b_in, w_rec, w_gate, b_gate, bias,
                       log_step, gamma, beta, out);
}

// Round 3
// 66.588 us; speedup vs baseline: 2.5096x; 2.5096x over previous
//
#include <hip/hip_runtime.h>

#define D        128
#define M_TILE   32
#define THREADS  512
#define B_ROWS   131072
#define NTILES   (B_ROWS / M_TILE)   // 4096
#define GRID_BLOCKS 512

typedef __bf16  bf16x8  __attribute__((ext_vector_type(8)));
typedef float   f32x4   __attribute__((ext_vector_type(4)));

#define LOG2E 1.4426950408889634f

__device__ __forceinline__ float fexp2(float x) { return __builtin_amdgcn_exp2f(x); }
__device__ __forceinline__ float frcp(float x)  { return __builtin_amdgcn_rcpf(x); }

// tanh(x) = 1 - 2/(e^{2x}+1); inf-safe (e->inf => rcp->0 => 1; e->0 => -1)
__device__ __forceinline__ float fast_tanh(float x) {
    float e = fexp2(x * (2.f * LOG2E));
    return 1.f - 2.f * frcp(e + 1.f);
}
__device__ __forceinline__ float fast_sigmoid(float x) {
    return frcp(1.f + fexp2(-LOG2E * x));
}

__global__ __launch_bounds__(THREADS, 4)
void liquid_cell(const float* __restrict__ x,      const float* __restrict__ st,
                 const float* __restrict__ w_in,   const float* __restrict__ b_in,
                 const float* __restrict__ w_rec,  const float* __restrict__ w_gate,
                 const float* __restrict__ b_gate, const float* __restrict__ bias,
                 const float* __restrict__ log_step,
                 const float* __restrict__ gamma,  const float* __restrict__ beta,
                 float* __restrict__ out)
{
    // A tiles: 32 rows x 256 bf16, XOR-swizzled (elem ^= (row&7)<<3, i.e. byte ^= (row&7)<<4)
    __shared__ __align__(16) __bf16 A1[M_TILE * 256];  // [x | tanh(state)]
    __shared__ __align__(16) __bf16 A2[M_TILE * 256];  // (gi - mu)*rstd   (gamma/beta folded into W/bias)
    __shared__ __align__(16) float  SBUF[M_TILE * 128]; // state f32, swizzled (elem ^= (row&7)<<2)

    const int tid  = threadIdx.x;
    const int lane = tid & 63;
    const int wave = tid >> 6;
    const int q    = lane >> 4;            // 0..3
    const int arow = lane & 15;
    const int hcol = wave * 16 + arow;     // output col / weight row owned by this lane
    const int koff = q * 8;

    // ---- per-thread output params (registers only) ----
    const float stepv = fast_sigmoid(log_step[hcol]);
    const float bd    = b_in[hcol] + bias[hcol];
    float       bg    = b_gate[hcol];

    // ---- persistent weight B-fragments; fold gamma into w_gate, beta into bg ----
    // B-frag for mfma_f32_16x16x32_bf16: lane holds B[k][n], n = lane&15, k = kb*32 + q*8 + j
    bf16x8 wd[8], wg[8];
    float betaAcc = 0.f;
    #pragma unroll
    for (int kb = 0; kb < 8; ++kb) {
        const int k = kb * 32 + koff;
        const float* s1 = (k < 128) ? (w_in  + hcol * 128 + k)
                                    : (w_rec + hcol * 128 + (k - 128));
        const float* s2 = w_gate + hcol * 256 + k;
        #pragma unroll
        for (int j = 0; j < 8; ++j) {
            wd[kb][j] = (__bf16)s1[j];
            const float wv = s2[j];
            wg[kb][j] = (__bf16)(wv * gamma[k + j]);
            betaAcc  += wv * beta[k + j];
        }
    }
    betaAcc += __shfl_xor(betaAcc, 16);
    betaAcc += __shfl_xor(betaAcc, 32);
    bg += betaAcc;   // gate_in = ((gi-mu)*rstd)·(γ⊙Wg)^T + (b_gate + β·Wg^T)

    const int r   = tid >> 4;              // row within tile, 0..31
    const int c0  = (tid & 15) * 8;        // 8-col chunk
    const int sw  = (r & 7) << 3;          // A write swizzle (bf16-elem units)
    const int swf = (r & 7) << 2;          // SBUF write swizzle (f32-elem units)
    const int rsw = (arow & 7) << 3;       // A read swizzle ((ms*16+arow)&7 == arow&7)

    for (int tile = blockIdx.x; tile < NTILES; tile += GRID_BLOCKS) {
        // ---- phase A: load + LN stats + bf16 fragments ----
        const float* xp = x  + ((long)tile * M_TILE + r) * D + c0;
        const float* sp = st + ((long)tile * M_TILE + r) * D + c0;
        const f32x4 xa = *(const f32x4*)xp, xb = *(const f32x4*)(xp + 4);
        const f32x4 sa = *(const f32x4*)sp, sb = *(const f32x4*)(sp + 4);

        float sum = 0.f, sq = 0.f;
        #pragma unroll
        for (int j = 0; j < 4; ++j) {
            sum += xa[j] + xb[j] + sa[j] + sb[j];
            sq  += xa[j]*xa[j] + xb[j]*xb[j] + sa[j]*sa[j] + sb[j]*sb[j];
        }
        #pragma unroll
        for (int m = 1; m < 16; m <<= 1) {
            sum += __shfl_xor(sum, m);
            sq  += __shfl_xor(sq,  m);
        }
        const float mu   = sum * (1.f / 256.f);
        const float rstd = __builtin_amdgcn_rsqf(sq * (1.f / 256.f) - mu * mu + 1e-5f);
        const float nmur = -mu * rstd;

        bf16x8 a1x, a1s, a2x, a2s;
        #pragma unroll
        for (int j = 0; j < 4; ++j) {
            a1x[j]     = (__bf16)xa[j];
            a1x[j + 4] = (__bf16)xb[j];
            a1s[j]     = (__bf16)fast_tanh(sa[j]);
            a1s[j + 4] = (__bf16)fast_tanh(sb[j]);
            a2x[j]     = (__bf16)(xa[j] * rstd + nmur);
            a2x[j + 4] = (__bf16)(xb[j] * rstd + nmur);
            a2s[j]     = (__bf16)(sa[j] * rstd + nmur);
            a2s[j + 4] = (__bf16)(sb[j] * rstd + nmur);
        }

        __syncthreads();   // previous iteration's LDS reads complete
        *(bf16x8*)&A1[(r * 256 +       c0) ^ sw] = a1x;
        *(bf16x8*)&A1[(r * 256 + 128 + c0) ^ sw] = a1s;
        *(bf16x8*)&A2[(r * 256 +       c0) ^ sw] = a2x;
        *(bf16x8*)&A2[(r * 256 + 128 + c0) ^ sw] = a2s;
        *(f32x4*)&SBUF[(r * 128 + c0)     ^ swf] = sa;
        *(f32x4*)&SBUF[(r * 128 + c0 + 4) ^ swf] = sb;
        __syncthreads();

        // ---- MFMA ----
        f32x4 acc1[2], acc2[2];
        #pragma unroll
        for (int ms = 0; ms < 2; ++ms) { acc1[ms] = (f32x4)(0.f); acc2[ms] = (f32x4)(0.f); }

        #pragma unroll
        for (int ms = 0; ms < 2; ++ms) {
            const int base = (ms * 16 + arow) * 256;
            #pragma unroll
            for (int kb = 0; kb < 8; ++kb) {
                bf16x8 a = *(const bf16x8*)&A1[base + ((kb * 32 + koff) ^ rsw)];
                acc1[ms] = __builtin_amdgcn_mfma_f32_16x16x32_bf16(a, wd[kb], acc1[ms], 0, 0, 0);
            }
            #pragma unroll
            for (int kb = 0; kb < 8; ++kb) {
                bf16x8 a = *(const bf16x8*)&A2[base + ((kb * 32 + koff) ^ rsw)];
                acc2[ms] = __builtin_amdgcn_mfma_f32_16x16x32_bf16(a, wg[kb], acc2[ms], 0, 0, 0);
            }
        }

        // ---- epilogue ----
        const long obase = (long)tile * M_TILE;
        #pragma unroll
        for (int ms = 0; ms < 2; ++ms) {
            #pragma unroll
            for (int rg = 0; rg < 4; ++rg) {
                const int row = ms * 16 + q * 4 + rg;
                const float s      = SBUF[(row * 128 + hcol) ^ ((row & 7) << 2)];
                const float target = fast_tanh(acc1[ms][rg] + bd);
                const float gate   = fast_sigmoid(acc2[ms][rg] + bg);
                const float blend  = fminf(stepv * gate, 1.f);
                out[(obase + row) * D + hcol] = s + blend * (target - s);
            }
        }
    }
}

extern "C" void kernel_launch(void* const* d_in, const int* in_sizes, int n_in,
                              void* d_out, int out_size, void* d_ws, size_t ws_size,
                              hipStream_t stream) {
    const float* x        = (const float*)d_in[0];
    const float* st       = (const float*)d_in[1];
    const float* w_in     = (const float*)d_in[2];
    const float* b_in     = (const float*)d_in[3];
    const float* w_rec    = (const float*)d_in[4];
    const float* w_gate   = (const float*)d_in[5];
    const float* b_gate   = (const float*)d_in[6];
    const float* bias     = (const float*)d_in[7];
    const float* log_step = (const float*)d_in[8];
    const float* gamma    = (const float*)d_in[9];
    const float* beta     = (const float*)d_in[10];
    float* out = (float*)d_out;

    hipLaunchKernelGGL(liquid_cell, dim3(GRID_BLOCKS), dim3(THREADS), 0, stream,
                       x, st, w_in, b_in, w_rec, w_gate, b_gate, bias,
                       log_step, gamma, beta, out);
}